// Round 5
// baseline (26735.721 us; speedup 1.0000x reference)
//
#include <hip/hip_runtime.h>

// Persistent-kernel LSTM autoencoder for MI355X — round 5.
// 8 groups x 2 WGs x 512 threads (8 waves). Group g = batches [16g,16g+16).
// WG half p owns h-cols [128p,128p+128); wave v owns cols 128p+16v..+16.
// Own-half h exchange: LDS + barrier. Peer-half (8 KB tagged u32 tile):
// dual-posted by producer (sc0 store -> local L2 path; sc0+sc1 -> MALL
// mirror); consumer tries 4 cached sc0 probes (fast if blocks g and g+8
// share an XCD), then falls back to the proven sc1 mirror poll. Tags in
// every word + parity double-buffer make both paths correct on ANY
// WG->XCD mapping (no fences, no flags). 0xAAAA poison never matches tags.

typedef unsigned int u32;
typedef unsigned long long u64;
typedef unsigned short u16;

typedef _Float16 v8h __attribute__((ext_vector_type(8)));
typedef float    v4f __attribute__((ext_vector_type(4)));
typedef u32      v4u __attribute__((ext_vector_type(4)));

union H8 { v8h v; u64 q[2]; v4u u4; u32 d[4]; _Float16 h[8]; u16 s[8]; };

#define TAG(sid) (0x4000u + (u32)(sid))

// ws layout (u32 units): Lbuf [g][p][3 slots][16][128]; Mbuf same at +98304.
static __device__ __forceinline__ u32* lbufp(u32* ws, int g, int p, int slot){
  return ws + (u64)((g*2 + p)*3 + slot)*2048u;
}
static __device__ __forceinline__ u32* mbufp(u32* ws, int g, int p, int slot){
  return ws + 98304u + (u64)((g*2 + p)*3 + slot)*2048u;
}

static __device__ __forceinline__ float fsig(float x){
  return __builtin_amdgcn_rcpf(1.f + __builtin_amdgcn_exp2f(-1.4426950408889634f*x));
}
static __device__ __forceinline__ float ftanh(float x){
  return 1.f - 2.f*__builtin_amdgcn_rcpf(1.f + __builtin_amdgcn_exp2f(2.8853900817779268f*x));
}
static __device__ __forceinline__ u32 f2tag(float f, u32 tag){
  union{ _Float16 h; u16 b; } u; u.h = (_Float16)f;
  return (tag << 16) | (u32)u.b;
}

// Dual post: local-L2 copy (sc0) + MALL mirror (sc0 sc1). Fire-and-forget.
static __device__ __forceinline__ void post(u32* lp, u32* mp, u32 v){
  asm volatile("global_store_dword %0, %2, off sc0\n\t"
               "global_store_dword %1, %2, off sc0 sc1"
               :: "v"(lp), "v"(mp), "v"(v) : "memory");
}

// Batched 8-KB half-tile read (8 x dwordx4, one vmcnt drain).
static __device__ __forceinline__ void ld8_fast(const u32* p, v4u q[8]){
  asm volatile(
    "global_load_dwordx4 %0, %8, off sc0\n\t"
    "global_load_dwordx4 %1, %8, off offset:16 sc0\n\t"
    "global_load_dwordx4 %2, %8, off offset:128 sc0\n\t"
    "global_load_dwordx4 %3, %8, off offset:144 sc0\n\t"
    "global_load_dwordx4 %4, %8, off offset:256 sc0\n\t"
    "global_load_dwordx4 %5, %8, off offset:272 sc0\n\t"
    "global_load_dwordx4 %6, %8, off offset:384 sc0\n\t"
    "global_load_dwordx4 %7, %8, off offset:400 sc0\n\t"
    "s_waitcnt vmcnt(0)"
    : "=v"(q[0]), "=v"(q[1]), "=v"(q[2]), "=v"(q[3]),
      "=v"(q[4]), "=v"(q[5]), "=v"(q[6]), "=v"(q[7])
    : "v"(p) : "memory");
}
static __device__ __forceinline__ void ld8_slow(const u32* p, v4u q[8]){
  asm volatile(
    "global_load_dwordx4 %0, %8, off sc0 sc1\n\t"
    "global_load_dwordx4 %1, %8, off offset:16 sc0 sc1\n\t"
    "global_load_dwordx4 %2, %8, off offset:128 sc0 sc1\n\t"
    "global_load_dwordx4 %3, %8, off offset:144 sc0 sc1\n\t"
    "global_load_dwordx4 %4, %8, off offset:256 sc0 sc1\n\t"
    "global_load_dwordx4 %5, %8, off offset:272 sc0 sc1\n\t"
    "global_load_dwordx4 %6, %8, off offset:384 sc0 sc1\n\t"
    "global_load_dwordx4 %7, %8, off offset:400 sc0 sc1\n\t"
    "s_waitcnt vmcnt(0)"
    : "=v"(q[0]), "=v"(q[1]), "=v"(q[2]), "=v"(q[3]),
      "=v"(q[4]), "=v"(q[5]), "=v"(q[6]), "=v"(q[7])
    : "v"(p) : "memory");
}

static __device__ __forceinline__ bool tags_ok(const v4u q[8], u32 tm){
  u32 bad = 0;
  #pragma unroll
  for (int i = 0; i < 8; ++i)
    #pragma unroll
    for (int j = 0; j < 4; ++j) bad |= (q[i][j] ^ tm);
  return __all((bad & 0xFFFF0000u) == 0);
}
static __device__ __forceinline__ void pack8(const v4u q[8], H8 A[4]){
  #pragma unroll
  for (int k = 0; k < 4; ++k){
    const v4u a = q[2*k], b = q[2*k+1];
    A[k].d[0] = (a[0] & 0xFFFFu) | (a[1] << 16);
    A[k].d[1] = (a[2] & 0xFFFFu) | (a[3] << 16);
    A[k].d[2] = (b[0] & 0xFFFFu) | (b[1] << 16);
    A[k].d[3] = (b[2] & 0xFFFFu) | (b[3] << 16);
  }
}

// Poll the peer 16x128 tagged tile: 4 cached probes, then sc1 mirror loop.
static __device__ __forceinline__ void read_peer(const u32* lb, const u32* mb,
                                                 u32 tag, int c, int quad, H8 A[4]){
  const int off = c*128 + quad*8;
  const u32 tm = tag << 16;
  v4u q[8];
  #pragma unroll 1
  for (int a = 0; a < 4; ++a){
    ld8_fast(lb + off, q);
    if (tags_ok(q, tm)){ pack8(q, A); return; }
  }
  #pragma unroll 1
  for(;;){
    ld8_slow(mb + off, q);
    if (tags_ok(q, tm)){ pack8(q, A); return; }
    __builtin_amdgcn_s_sleep(1);
  }
}

// 4x11 B-fragments (N=[i|f|g|o] at col wcolc, K=[inp 0..95 pad | h 96..351]).
static __device__ __forceinline__ void build_Bw(v8h Bw[4][11], const float* Wih,
                                                const float* Whh, int wcolc, int quad){
  #pragma unroll
  for (int nt = 0; nt < 4; ++nt){
    const int n = nt*256 + wcolc;
    #pragma unroll
    for (int kt = 0; kt < 11; ++kt){
      const int k0 = kt*32 + quad*8;
      H8 a;
      #pragma unroll
      for (int j = 0; j < 8; ++j){
        const int k = k0 + j;
        float v;
        if (kt < 3) v = (k < 88) ? Wih[n*88 + k] : 0.f;
        else        v = Whh[n*256 + (k - 96)];
        a.h[j] = (_Float16)v;
      }
      Bw[nt][kt] = a.v;
    }
  }
}

__global__ __launch_bounds__(512, 2) void lstm_ae(
    const float* __restrict__ x,
    const float* __restrict__ Wih_e, const float* __restrict__ Whh_e,
    const float* __restrict__ bih_e, const float* __restrict__ bhh_e,
    const float* __restrict__ Wih_d, const float* __restrict__ Whh_d,
    const float* __restrict__ bih_d, const float* __restrict__ bhh_d,
    const float* __restrict__ W_lat, const float* __restrict__ b_lat,
    const float* __restrict__ W_decinit, const float* __restrict__ b_decinit,
    const float* __restrict__ W_out, const float* __restrict__ b_out,
    float* __restrict__ dout, char* __restrict__ ws)
{
  const int tid = (int)threadIdx.x;
  const int v = tid >> 6, l = tid & 63;
  const int c = l & 15, quad = (l >> 4) & 3;
  const int g = (int)blockIdx.x & 7, p = (int)blockIdx.x >> 3;
  const int wcolc = p*128 + v*16 + c;       // absolute gate/h column
  const int lcol  = v*16 + c;               // column within own half

  u32* wsu = (u32*)ws;

  __shared__ v4u      woutlds[3072];                 // 48 KB W_out B-frags
  __shared__ alignas(16) _Float16 hlds[2][16][136];  // own-half h dbuf (pad 8)
  __shared__ alignas(16) _Float16 zlds[16][136];
  __shared__ alignas(16) _Float16 predlds[16][104];

  // ---- prologue: W_out -> LDS (wave v builds frags [6v,6v+6)) ----
  #pragma unroll
  for (int fi = 0; fi < 6; ++fi){
    const int fid = v*6 + fi, nt = fid >> 3, kt = fid & 7;
    const int n = nt*16 + c, k0 = kt*32 + quad*8;
    H8 a;
    #pragma unroll
    for (int j = 0; j < 8; ++j){
      float vv = (n < 88) ? W_out[n*256 + k0 + j] : 0.f;
      a.h[j] = (_Float16)vv;
    }
    woutlds[fid*64 + l] = a.u4;
  }

  v8h Bw[4][11];
  build_Bw(Bw, Wih_e, Whh_e, wcolc, quad);
  float be[4];
  #pragma unroll
  for (int nt = 0; nt < 4; ++nt){ const int n = nt*256 + wcolc; be[nt] = bih_e[n] + bhh_e[n]; }

  float cst[4] = {0.f, 0.f, 0.f, 0.f};
  __syncthreads();

  // ================= encoder =================
  #pragma unroll 1
  for (int t = 0; t < 1024; ++t){
    H8 Ax[3];
    {
      const float* xb = x + ((u64)(g*16 + c)*1024u + (u64)t)*88u;
      #pragma unroll
      for (int kt = 0; kt < 3; ++kt){
        const int k0 = kt*32 + quad*8;
        if (kt == 2 && quad == 3){ Ax[kt].q[0] = 0; Ax[kt].q[1] = 0; }
        else {
          v4f f0 = *(const v4f*)(xb + k0);
          v4f f1 = *(const v4f*)(xb + k0 + 4);
          #pragma unroll
          for (int j = 0; j < 4; ++j){ Ax[kt].h[j] = (_Float16)f0[j]; Ax[kt].h[j+4] = (_Float16)f1[j]; }
        }
      }
    }

    v4f acc[4];
    #pragma unroll
    for (int nt = 0; nt < 4; ++nt) acc[nt] = (v4f){0.f,0.f,0.f,0.f};
    #pragma unroll
    for (int kt = 0; kt < 3; ++kt)
      #pragma unroll
      for (int nt = 0; nt < 4; ++nt)
        acc[nt] = __builtin_amdgcn_mfma_f32_16x16x32_f16(Ax[kt].v, Bw[nt][kt], acc[nt], 0, 0, 0);

    if (t > 0){
      const int sl = (t-1) & 1;
      H8 Aho[4];
      const _Float16* hr = &hlds[sl][c][0];
      #pragma unroll
      for (int j = 0; j < 4; ++j) Aho[j].u4 = *(const v4u*)(hr + 32*j + quad*8);
      #pragma unroll
      for (int j = 0; j < 4; ++j)
        #pragma unroll
        for (int nt = 0; nt < 4; ++nt)
          acc[nt] = __builtin_amdgcn_mfma_f32_16x16x32_f16(Aho[j].v, Bw[nt][3 + 4*p + j], acc[nt], 0, 0, 0);

      H8 Ahp[4];
      read_peer(lbufp(wsu,g,1-p,sl), mbufp(wsu,g,1-p,sl), TAG(t-1), c, quad, Ahp);
      #pragma unroll
      for (int j = 0; j < 4; ++j)
        #pragma unroll
        for (int nt = 0; nt < 4; ++nt)
          acc[nt] = __builtin_amdgcn_mfma_f32_16x16x32_f16(Ahp[j].v, Bw[nt][3 + 4*(1-p) + j], acc[nt], 0, 0, 0);
    }

    u32* Lw = lbufp(wsu, g, p, t & 1);
    u32* Mw = mbufp(wsu, g, p, t & 1);
    const u32 tg = TAG(t);
    #pragma unroll
    for (int r = 0; r < 4; ++r){
      const float gi = acc[0][r] + be[0];
      const float gf = acc[1][r] + be[1];
      const float gg = acc[2][r] + be[2];
      const float go = acc[3][r] + be[3];
      const float cn = fsig(gf)*cst[r] + fsig(gi)*ftanh(gg);
      cst[r] = cn;
      const float hn = fsig(go)*ftanh(cn);
      const int m = quad*4 + r;
      hlds[t & 1][m][lcol] = (_Float16)hn;
      const int off = m*128 + lcol;
      post(Lw + off, Mw + off, f2tag(hn, tg));
    }
    __syncthreads();
  }

  // ---- latent: z = h_n @ W_lat.T + b_lat (each wave: one 16-col z-tile) ----
  {
    H8 Aho[4], Ahp[4];
    const _Float16* hr = &hlds[1][c][0];
    #pragma unroll
    for (int j = 0; j < 4; ++j) Aho[j].u4 = *(const v4u*)(hr + 32*j + quad*8);
    read_peer(lbufp(wsu,g,1-p,1), mbufp(wsu,g,1-p,1), TAG(1023), c, quad, Ahp);
    v8h Ahg[8];
    #pragma unroll
    for (int j = 0; j < 4; ++j){ Ahg[4*p + j] = Aho[j].v; Ahg[4*(1-p) + j] = Ahp[j].v; }

    const int zn = v*16 + c;   // z column, < 128
    v4f zacc = (v4f){0.f,0.f,0.f,0.f};
    #pragma unroll
    for (int k = 0; k < 8; ++k){
      H8 b;
      const int k0 = k*32 + quad*8;
      v4f f0 = *(const v4f*)(W_lat + zn*256 + k0);
      v4f f1 = *(const v4f*)(W_lat + zn*256 + k0 + 4);
      #pragma unroll
      for (int j = 0; j < 4; ++j){ b.h[j] = (_Float16)f0[j]; b.h[j+4] = (_Float16)f1[j]; }
      zacc = __builtin_amdgcn_mfma_f32_16x16x32_f16(Ahg[k], b.v, zacc, 0, 0, 0);
    }
    const float bl = b_lat[zn];
    #pragma unroll
    for (int r = 0; r < 4; ++r){
      const int m = quad*4 + r;
      const float zv = zacc[r] + bl;
      if (p == 0)
        __builtin_nontemporal_store(zv, dout + 11534336u + (u64)(g*16 + m)*128u + zn);
      zlds[m][zn] = (_Float16)zv;
    }
  }

  // ---- switch weights to decoder ----
  build_Bw(Bw, Wih_d, Whh_d, wcolc, quad);
  float bd[4];
  #pragma unroll
  for (int nt = 0; nt < 4; ++nt){ const int n = nt*256 + wcolc; bd[nt] = bih_d[n] + bhh_d[n]; }
  const float bov = (v < 6 && (v*16 + c) < 88) ? b_out[v*16 + c] : 0.f;
  __syncthreads();

  // ---- decoder init: h0 = z @ W_decinit.T + b_decinit ----
  {
    H8 Az[4];
    #pragma unroll
    for (int kt = 0; kt < 4; ++kt)
      Az[kt].u4 = *(const v4u*)(&zlds[c][kt*32 + quad*8]);
    v4f da = (v4f){0.f,0.f,0.f,0.f};
    #pragma unroll
    for (int kt = 0; kt < 4; ++kt){
      H8 b;
      const int k0 = kt*32 + quad*8;
      v4f f0 = *(const v4f*)(W_decinit + wcolc*128 + k0);
      v4f f1 = *(const v4f*)(W_decinit + wcolc*128 + k0 + 4);
      #pragma unroll
      for (int j = 0; j < 4; ++j){ b.h[j] = (_Float16)f0[j]; b.h[j+4] = (_Float16)f1[j]; }
      da = __builtin_amdgcn_mfma_f32_16x16x32_f16(Az[kt].v, b.v, da, 0, 0, 0);
    }
    const float bdi = b_decinit[wcolc];
    u32* Lw = lbufp(wsu, g, p, 2);
    u32* Mw = mbufp(wsu, g, p, 2);
    #pragma unroll
    for (int r = 0; r < 4; ++r){
      const int m = quad*4 + r;
      const float hv = da[r] + bdi;
      hlds[1][m][lcol] = (_Float16)hv;
      const int off = m*128 + lcol;
      post(Lw + off, Mw + off, f2tag(hv, TAG(1025)));
    }
  }
  #pragma unroll
  for (int r = 0; r < 4; ++r) cst[r] = 0.f;
  __syncthreads();

  // ================= decoder =================
  #pragma unroll 1
  for (int t = 0; t < 1024; ++t){
    const int sl = (t-1) & 1;                 // LDS slot of h(t-1) (t=0 -> 1)
    const int gsl = (t == 0) ? 2 : sl;        // global slot (h0 lives in 2)
    H8 Aho[4], Ahp[4];
    const _Float16* hr = &hlds[sl][c][0];
    #pragma unroll
    for (int j = 0; j < 4; ++j) Aho[j].u4 = *(const v4u*)(hr + 32*j + quad*8);
    read_peer(lbufp(wsu,g,1-p,gsl), mbufp(wsu,g,1-p,gsl), TAG(1025 + t), c, quad, Ahp);

    if (t > 0 && v < 6){
      v8h Ahg[8];
      #pragma unroll
      for (int j = 0; j < 4; ++j){ Ahg[4*p + j] = Aho[j].v; Ahg[4*(1-p) + j] = Ahp[j].v; }
      v4f pacc = (v4f){0.f,0.f,0.f,0.f};
      #pragma unroll
      for (int k = 0; k < 8; ++k){
        H8 b; b.u4 = woutlds[(v*8 + k)*64 + l];
        pacc = __builtin_amdgcn_mfma_f32_16x16x32_f16(Ahg[k], b.v, pacc, 0, 0, 0);
      }
      const int col = v*16 + c;
      #pragma unroll
      for (int r = 0; r < 4; ++r){
        const float pv = fsig(pacc[r] + bov);
        const int m = quad*4 + r;
        predlds[m][col] = (_Float16)pv;
        if (col < 88)
          __builtin_nontemporal_store(pv,
            dout + ((u64)(g*16 + m)*1024u + (u64)(t-1))*88u + col);
      }
    }
    __syncthreads();

    H8 Ap[3];
    if (t == 0){
      #pragma unroll
      for (int kt = 0; kt < 3; ++kt){ Ap[kt].q[0] = 0; Ap[kt].q[1] = 0; }
    } else {
      #pragma unroll
      for (int kt = 0; kt < 3; ++kt)
        Ap[kt].u4 = *(const v4u*)(&predlds[c][kt*32 + quad*8]);
    }

    v4f acc[4];
    #pragma unroll
    for (int nt = 0; nt < 4; ++nt) acc[nt] = (v4f){0.f,0.f,0.f,0.f};
    #pragma unroll
    for (int kt = 0; kt < 3; ++kt)
      #pragma unroll
      for (int nt = 0; nt < 4; ++nt)
        acc[nt] = __builtin_amdgcn_mfma_f32_16x16x32_f16(Ap[kt].v, Bw[nt][kt], acc[nt], 0, 0, 0);
    #pragma unroll
    for (int j = 0; j < 4; ++j)
      #pragma unroll
      for (int nt = 0; nt < 4; ++nt)
        acc[nt] = __builtin_amdgcn_mfma_f32_16x16x32_f16(Aho[j].v, Bw[nt][3 + 4*p + j], acc[nt], 0, 0, 0);
    #pragma unroll
    for (int j = 0; j < 4; ++j)
      #pragma unroll
      for (int nt = 0; nt < 4; ++nt)
        acc[nt] = __builtin_amdgcn_mfma_f32_16x16x32_f16(Ahp[j].v, Bw[nt][3 + 4*(1-p) + j], acc[nt], 0, 0, 0);

    u32* Lw = lbufp(wsu, g, p, t & 1);
    u32* Mw = mbufp(wsu, g, p, t & 1);
    const u32 wtg = TAG(1026 + t);
    #pragma unroll
    for (int r = 0; r < 4; ++r){
      const float gi = acc[0][r] + bd[0];
      const float gf = acc[1][r] + bd[1];
      const float gg = acc[2][r] + bd[2];
      const float go = acc[3][r] + bd[3];
      const float cn = fsig(gf)*cst[r] + fsig(gi)*ftanh(gg);
      cst[r] = cn;
      const float hn = fsig(go)*ftanh(cn);
      const int m = quad*4 + r;
      hlds[t & 1][m][lcol] = (_Float16)hn;
      const int off = m*128 + lcol;
      post(Lw + off, Mw + off, f2tag(hn, wtg));
    }
    __syncthreads();
  }

  // ---- tail: pred(1023) -> output row 1023 ----
  {
    H8 Aho[4], Ahp[4];
    const _Float16* hr = &hlds[1][c][0];
    #pragma unroll
    for (int j = 0; j < 4; ++j) Aho[j].u4 = *(const v4u*)(hr + 32*j + quad*8);
    read_peer(lbufp(wsu,g,1-p,1), mbufp(wsu,g,1-p,1), TAG(2049), c, quad, Ahp);
    if (v < 6){
      v8h Ahg[8];
      #pragma unroll
      for (int j = 0; j < 4; ++j){ Ahg[4*p + j] = Aho[j].v; Ahg[4*(1-p) + j] = Ahp[j].v; }
      v4f pacc = (v4f){0.f,0.f,0.f,0.f};
      #pragma unroll
      for (int k = 0; k < 8; ++k){
        H8 b; b.u4 = woutlds[(v*8 + k)*64 + l];
        pacc = __builtin_amdgcn_mfma_f32_16x16x32_f16(Ahg[k], b.v, pacc, 0, 0, 0);
      }
      const int col = v*16 + c;
      if (col < 88){
        #pragma unroll
        for (int r = 0; r < 4; ++r){
          const float pv = fsig(pacc[r] + bov);
          const int m = quad*4 + r;
          __builtin_nontemporal_store(pv,
            dout + ((u64)(g*16 + m)*1024u + 1023u)*88u + col);
        }
      }
    }
  }
}

extern "C" void kernel_launch(void* const* d_in, const int* in_sizes, int n_in,
                              void* d_out, int out_size, void* d_ws, size_t ws_size,
                              hipStream_t stream){
  (void)in_sizes; (void)n_in; (void)out_size; (void)ws_size;
  hipLaunchKernelGGL(lstm_ae, dim3(16), dim3(512), 0, stream,
    (const float*)d_in[0],  (const float*)d_in[1],  (const float*)d_in[2],
    (const float*)d_in[3],  (const float*)d_in[4],  (const float*)d_in[5],
    (const float*)d_in[6],  (const float*)d_in[7],  (const float*)d_in[8],
    (const float*)d_in[9],  (const float*)d_in[10], (const float*)d_in[11],
    (const float*)d_in[12], (const float*)d_in[13], (const float*)d_in[14],
    (float*)d_out, (char*)d_ws);
}

// Round 6
// 13396.909 us; speedup vs baseline: 1.9957x; 1.9957x over previous
//
#include <hip/hip_runtime.h>

// Persistent-kernel LSTM autoencoder for MI355X — round 6.
// Round-5 topology (8 groups x 2 WGs x 512 thr; own half via LDS+barrier,
// peer 8KB half dual-posted sc0-local + sc0sc1-MALL, 4 cached probes then
// sc1 fallback; tags+parity => correct on any XCD mapping) with the fatal
// round-5 bug fixed: ALL register-array indices are now compile-time.
// K-fragments are ordered OWN-HALF-FIRST (slots 3-6) / PEER-SECOND (7-10),
// with the WG half `p` folded into weight ADDRESSES, not register indices.
// Round-5 evidence: FETCH collapsed to 72MB (same-XCD probe hits work);
// VGPR=124 proved Bw spilled to scratch (runtime-indexed reg array).

typedef unsigned int u32;
typedef unsigned long long u64;
typedef unsigned short u16;

typedef _Float16 v8h __attribute__((ext_vector_type(8)));
typedef float    v4f __attribute__((ext_vector_type(4)));
typedef u32      v4u __attribute__((ext_vector_type(4)));

union H8 { v8h v; u64 q[2]; v4u u4; u32 d[4]; _Float16 h[8]; u16 s[8]; };

#define TAG(sid) (0x4000u + (u32)(sid))

// ws layout (u32 units): Lbuf [g][p][3 slots][16][128]; Mbuf same at +98304.
static __device__ __forceinline__ u32* lbufp(u32* ws, int g, int p, int slot){
  return ws + (u64)((g*2 + p)*3 + slot)*2048u;
}
static __device__ __forceinline__ u32* mbufp(u32* ws, int g, int p, int slot){
  return ws + 98304u + (u64)((g*2 + p)*3 + slot)*2048u;
}

static __device__ __forceinline__ float fsig(float x){
  return __builtin_amdgcn_rcpf(1.f + __builtin_amdgcn_exp2f(-1.4426950408889634f*x));
}
static __device__ __forceinline__ float ftanh(float x){
  return 1.f - 2.f*__builtin_amdgcn_rcpf(1.f + __builtin_amdgcn_exp2f(2.8853900817779268f*x));
}
static __device__ __forceinline__ u32 f2tag(float f, u32 tag){
  union{ _Float16 h; u16 b; } u; u.h = (_Float16)f;
  return (tag << 16) | (u32)u.b;
}

// Dual post: local-L2 copy (sc0) + MALL mirror (sc0 sc1). Fire-and-forget.
static __device__ __forceinline__ void post(u32* lp, u32* mp, u32 v){
  asm volatile("global_store_dword %0, %2, off sc0\n\t"
               "global_store_dword %1, %2, off sc0 sc1"
               :: "v"(lp), "v"(mp), "v"(v) : "memory");
}

// Batched 8-KB half-tile read (8 x dwordx4, one vmcnt drain).
static __device__ __forceinline__ void ld8_fast(const u32* p, v4u q[8]){
  asm volatile(
    "global_load_dwordx4 %0, %8, off sc0\n\t"
    "global_load_dwordx4 %1, %8, off offset:16 sc0\n\t"
    "global_load_dwordx4 %2, %8, off offset:128 sc0\n\t"
    "global_load_dwordx4 %3, %8, off offset:144 sc0\n\t"
    "global_load_dwordx4 %4, %8, off offset:256 sc0\n\t"
    "global_load_dwordx4 %5, %8, off offset:272 sc0\n\t"
    "global_load_dwordx4 %6, %8, off offset:384 sc0\n\t"
    "global_load_dwordx4 %7, %8, off offset:400 sc0\n\t"
    "s_waitcnt vmcnt(0)"
    : "=v"(q[0]), "=v"(q[1]), "=v"(q[2]), "=v"(q[3]),
      "=v"(q[4]), "=v"(q[5]), "=v"(q[6]), "=v"(q[7])
    : "v"(p) : "memory");
}
static __device__ __forceinline__ void ld8_slow(const u32* p, v4u q[8]){
  asm volatile(
    "global_load_dwordx4 %0, %8, off sc0 sc1\n\t"
    "global_load_dwordx4 %1, %8, off offset:16 sc0 sc1\n\t"
    "global_load_dwordx4 %2, %8, off offset:128 sc0 sc1\n\t"
    "global_load_dwordx4 %3, %8, off offset:144 sc0 sc1\n\t"
    "global_load_dwordx4 %4, %8, off offset:256 sc0 sc1\n\t"
    "global_load_dwordx4 %5, %8, off offset:272 sc0 sc1\n\t"
    "global_load_dwordx4 %6, %8, off offset:384 sc0 sc1\n\t"
    "global_load_dwordx4 %7, %8, off offset:400 sc0 sc1\n\t"
    "s_waitcnt vmcnt(0)"
    : "=v"(q[0]), "=v"(q[1]), "=v"(q[2]), "=v"(q[3]),
      "=v"(q[4]), "=v"(q[5]), "=v"(q[6]), "=v"(q[7])
    : "v"(p) : "memory");
}

static __device__ __forceinline__ bool tags_ok(const v4u q[8], u32 tm){
  u32 bad = 0;
  #pragma unroll
  for (int i = 0; i < 8; ++i)
    #pragma unroll
    for (int j = 0; j < 4; ++j) bad |= (q[i][j] ^ tm);
  return __all((bad & 0xFFFF0000u) == 0);
}
static __device__ __forceinline__ void pack8(const v4u q[8], H8 A[4]){
  #pragma unroll
  for (int k = 0; k < 4; ++k){
    const v4u a = q[2*k], b = q[2*k+1];
    A[k].d[0] = (a[0] & 0xFFFFu) | (a[1] << 16);
    A[k].d[1] = (a[2] & 0xFFFFu) | (a[3] << 16);
    A[k].d[2] = (b[0] & 0xFFFFu) | (b[1] << 16);
    A[k].d[3] = (b[2] & 0xFFFFu) | (b[3] << 16);
  }
}

// Poll the peer 16x128 tagged tile: 4 cached probes, then sc1 mirror loop.
static __device__ __forceinline__ void read_peer(const u32* lb, const u32* mb,
                                                 u32 tag, int c, int quad, H8 A[4]){
  const int off = c*128 + quad*8;
  const u32 tm = tag << 16;
  v4u q[8];
  #pragma unroll 1
  for (int a = 0; a < 4; ++a){
    ld8_fast(lb + off, q);
    if (tags_ok(q, tm)){ pack8(q, A); return; }
  }
  #pragma unroll 1
  for(;;){
    ld8_slow(mb + off, q);
    if (tags_ok(q, tm)){ pack8(q, A); return; }
    __builtin_amdgcn_s_sleep(1);
  }
}

// 4x11 B-fragments, K-slot order: 0-2 input (88 pad 96), 3-6 OWN Whh half
// (cols 128p..), 7-10 PEER half (cols 128(1-p)..). p only in addresses.
static __device__ __forceinline__ void build_Bw(v8h Bw[4][11], const float* Wih,
                                                const float* Whh, int wcolc,
                                                int quad, int p){
  #pragma unroll
  for (int nt = 0; nt < 4; ++nt){
    const int n = nt*256 + wcolc;
    #pragma unroll
    for (int kt = 0; kt < 11; ++kt){
      H8 a;
      #pragma unroll
      for (int j = 0; j < 8; ++j){
        float v;
        if (kt < 3){
          const int k = kt*32 + quad*8 + j;
          v = (k < 88) ? Wih[n*88 + k] : 0.f;
        } else if (kt < 7){
          const int k = 128*p + (kt-3)*32 + quad*8 + j;
          v = Whh[n*256 + k];
        } else {
          const int k = 128*(1-p) + (kt-7)*32 + quad*8 + j;
          v = Whh[n*256 + k];
        }
        a.h[j] = (_Float16)v;
      }
      Bw[nt][kt] = a.v;
    }
  }
}

__global__ __launch_bounds__(512, 2) void lstm_ae(
    const float* __restrict__ x,
    const float* __restrict__ Wih_e, const float* __restrict__ Whh_e,
    const float* __restrict__ bih_e, const float* __restrict__ bhh_e,
    const float* __restrict__ Wih_d, const float* __restrict__ Whh_d,
    const float* __restrict__ bih_d, const float* __restrict__ bhh_d,
    const float* __restrict__ W_lat, const float* __restrict__ b_lat,
    const float* __restrict__ W_decinit, const float* __restrict__ b_decinit,
    const float* __restrict__ W_out, const float* __restrict__ b_out,
    float* __restrict__ dout, char* __restrict__ ws)
{
  const int tid = (int)threadIdx.x;
  const int v = tid >> 6, l = tid & 63;
  const int c = l & 15, quad = (l >> 4) & 3;
  const int g = (int)blockIdx.x & 7, p = (int)blockIdx.x >> 3;
  const int wcolc = p*128 + v*16 + c;       // absolute gate/h column
  const int lcol  = v*16 + c;               // column within own half

  u32* wsu = (u32*)ws;

  __shared__ v4u      woutlds[3072];                 // 48 KB W_out B-frags
  __shared__ alignas(16) _Float16 hlds[2][16][136];  // own-half h dbuf (pad 8)
  __shared__ alignas(16) _Float16 zlds[16][136];
  __shared__ alignas(16) _Float16 predlds[16][104];

  // ---- prologue: W_out -> LDS, K-slots own-first (wave v: frags 6v..6v+6) --
  #pragma unroll
  for (int fi = 0; fi < 6; ++fi){
    const int fid = v*6 + fi, nt = fid >> 3, kt = fid & 7;
    const int n = nt*16 + c;
    const int k0 = ((kt < 4) ? 128*p : 128*(1-p)) + (kt & 3)*32 + quad*8;
    H8 a;
    #pragma unroll
    for (int j = 0; j < 8; ++j){
      float vv = (n < 88) ? W_out[n*256 + k0 + j] : 0.f;
      a.h[j] = (_Float16)vv;
    }
    woutlds[fid*64 + l] = a.u4;
  }

  v8h Bw[4][11];
  build_Bw(Bw, Wih_e, Whh_e, wcolc, quad, p);
  float be[4];
  #pragma unroll
  for (int nt = 0; nt < 4; ++nt){ const int n = nt*256 + wcolc; be[nt] = bih_e[n] + bhh_e[n]; }

  float cst[4] = {0.f, 0.f, 0.f, 0.f};
  __syncthreads();

  // ================= encoder =================
  #pragma unroll 1
  for (int t = 0; t < 1024; ++t){
    H8 Ax[3];
    {
      const float* xb = x + ((u64)(g*16 + c)*1024u + (u64)t)*88u;
      #pragma unroll
      for (int kt = 0; kt < 3; ++kt){
        const int k0 = kt*32 + quad*8;
        if (kt == 2 && quad == 3){ Ax[kt].q[0] = 0; Ax[kt].q[1] = 0; }
        else {
          v4f f0 = *(const v4f*)(xb + k0);
          v4f f1 = *(const v4f*)(xb + k0 + 4);
          #pragma unroll
          for (int j = 0; j < 4; ++j){ Ax[kt].h[j] = (_Float16)f0[j]; Ax[kt].h[j+4] = (_Float16)f1[j]; }
        }
      }
    }

    v4f acc[4];
    #pragma unroll
    for (int nt = 0; nt < 4; ++nt) acc[nt] = (v4f){0.f,0.f,0.f,0.f};
    #pragma unroll
    for (int kt = 0; kt < 3; ++kt)
      #pragma unroll
      for (int nt = 0; nt < 4; ++nt)
        acc[nt] = __builtin_amdgcn_mfma_f32_16x16x32_f16(Ax[kt].v, Bw[nt][kt], acc[nt], 0, 0, 0);

    if (t > 0){
      const int sl = (t-1) & 1;
      H8 Aho[4];
      const _Float16* hr = &hlds[sl][c][0];
      #pragma unroll
      for (int j = 0; j < 4; ++j) Aho[j].u4 = *(const v4u*)(hr + 32*j + quad*8);
      #pragma unroll
      for (int j = 0; j < 4; ++j)
        #pragma unroll
        for (int nt = 0; nt < 4; ++nt)
          acc[nt] = __builtin_amdgcn_mfma_f32_16x16x32_f16(Aho[j].v, Bw[nt][3 + j], acc[nt], 0, 0, 0);

      H8 Ahp[4];
      read_peer(lbufp(wsu,g,1-p,sl), mbufp(wsu,g,1-p,sl), TAG(t-1), c, quad, Ahp);
      #pragma unroll
      for (int j = 0; j < 4; ++j)
        #pragma unroll
        for (int nt = 0; nt < 4; ++nt)
          acc[nt] = __builtin_amdgcn_mfma_f32_16x16x32_f16(Ahp[j].v, Bw[nt][7 + j], acc[nt], 0, 0, 0);
    }

    u32* Lw = lbufp(wsu, g, p, t & 1);
    u32* Mw = mbufp(wsu, g, p, t & 1);
    const u32 tg = TAG(t);
    #pragma unroll
    for (int r = 0; r < 4; ++r){
      const float gi = acc[0][r] + be[0];
      const float gf = acc[1][r] + be[1];
      const float gg = acc[2][r] + be[2];
      const float go = acc[3][r] + be[3];
      const float cn = fsig(gf)*cst[r] + fsig(gi)*ftanh(gg);
      cst[r] = cn;
      const float hn = fsig(go)*ftanh(cn);
      const int m = quad*4 + r;
      hlds[t & 1][m][lcol] = (_Float16)hn;
      const int off = m*128 + lcol;
      post(Lw + off, Mw + off, f2tag(hn, tg));
    }
    __syncthreads();
  }

  // ---- latent: z = h_n @ W_lat.T + b_lat (each wave: one 16-col z-tile) ----
  {
    H8 Aho[4], Ahp[4];
    const _Float16* hr = &hlds[1][c][0];
    #pragma unroll
    for (int j = 0; j < 4; ++j) Aho[j].u4 = *(const v4u*)(hr + 32*j + quad*8);
    read_peer(lbufp(wsu,g,1-p,1), mbufp(wsu,g,1-p,1), TAG(1023), c, quad, Ahp);

    const int zn = v*16 + c;   // z column, < 128
    v4f zacc = (v4f){0.f,0.f,0.f,0.f};
    #pragma unroll
    for (int k = 0; k < 4; ++k){          // own half, K = 128p + 32k ..
      H8 b;
      const int k0 = 128*p + k*32 + quad*8;
      v4f f0 = *(const v4f*)(W_lat + zn*256 + k0);
      v4f f1 = *(const v4f*)(W_lat + zn*256 + k0 + 4);
      #pragma unroll
      for (int j = 0; j < 4; ++j){ b.h[j] = (_Float16)f0[j]; b.h[j+4] = (_Float16)f1[j]; }
      zacc = __builtin_amdgcn_mfma_f32_16x16x32_f16(Aho[k].v, b.v, zacc, 0, 0, 0);
    }
    #pragma unroll
    for (int k = 0; k < 4; ++k){          // peer half
      H8 b;
      const int k0 = 128*(1-p) + k*32 + quad*8;
      v4f f0 = *(const v4f*)(W_lat + zn*256 + k0);
      v4f f1 = *(const v4f*)(W_lat + zn*256 + k0 + 4);
      #pragma unroll
      for (int j = 0; j < 4; ++j){ b.h[j] = (_Float16)f0[j]; b.h[j+4] = (_Float16)f1[j]; }
      zacc = __builtin_amdgcn_mfma_f32_16x16x32_f16(Ahp[k].v, b.v, zacc, 0, 0, 0);
    }
    const float bl = b_lat[zn];
    #pragma unroll
    for (int r = 0; r < 4; ++r){
      const int m = quad*4 + r;
      const float zv = zacc[r] + bl;
      if (p == 0)
        __builtin_nontemporal_store(zv, dout + 11534336u + (u64)(g*16 + m)*128u + zn);
      zlds[m][zn] = (_Float16)zv;
    }
  }

  // ---- switch weights to decoder ----
  build_Bw(Bw, Wih_d, Whh_d, wcolc, quad, p);
  float bd[4];
  #pragma unroll
  for (int nt = 0; nt < 4; ++nt){ const int n = nt*256 + wcolc; bd[nt] = bih_d[n] + bhh_d[n]; }
  const float bov = (v < 6 && (v*16 + c) < 88) ? b_out[v*16 + c] : 0.f;
  __syncthreads();

  // ---- decoder init: h0 = z @ W_decinit.T + b_decinit ----
  {
    H8 Az[4];
    #pragma unroll
    for (int kt = 0; kt < 4; ++kt)
      Az[kt].u4 = *(const v4u*)(&zlds[c][kt*32 + quad*8]);
    v4f da = (v4f){0.f,0.f,0.f,0.f};
    #pragma unroll
    for (int kt = 0; kt < 4; ++kt){
      H8 b;
      const int k0 = kt*32 + quad*8;
      v4f f0 = *(const v4f*)(W_decinit + wcolc*128 + k0);
      v4f f1 = *(const v4f*)(W_decinit + wcolc*128 + k0 + 4);
      #pragma unroll
      for (int j = 0; j < 4; ++j){ b.h[j] = (_Float16)f0[j]; b.h[j+4] = (_Float16)f1[j]; }
      da = __builtin_amdgcn_mfma_f32_16x16x32_f16(Az[kt].v, b.v, da, 0, 0, 0);
    }
    const float bdi = b_decinit[wcolc];
    u32* Lw = lbufp(wsu, g, p, 2);
    u32* Mw = mbufp(wsu, g, p, 2);
    #pragma unroll
    for (int r = 0; r < 4; ++r){
      const int m = quad*4 + r;
      const float hv = da[r] + bdi;
      hlds[1][m][lcol] = (_Float16)hv;
      const int off = m*128 + lcol;
      post(Lw + off, Mw + off, f2tag(hv, TAG(1025)));
    }
  }
  #pragma unroll
  for (int r = 0; r < 4; ++r) cst[r] = 0.f;
  __syncthreads();

  // ================= decoder =================
  #pragma unroll 1
  for (int t = 0; t < 1024; ++t){
    const int sl = (t-1) & 1;                 // LDS slot of h(t-1) (t=0 -> 1)
    const int gsl = (t == 0) ? 2 : sl;        // global slot (h0 lives in 2)
    H8 Aho[4], Ahp[4];
    const _Float16* hr = &hlds[sl][c][0];
    #pragma unroll
    for (int j = 0; j < 4; ++j) Aho[j].u4 = *(const v4u*)(hr + 32*j + quad*8);
    read_peer(lbufp(wsu,g,1-p,gsl), mbufp(wsu,g,1-p,gsl), TAG(1025 + t), c, quad, Ahp);

    if (t > 0 && v < 6){
      v4f pacc = (v4f){0.f,0.f,0.f,0.f};
      #pragma unroll
      for (int k = 0; k < 4; ++k){          // own-half K slots 0-3
        H8 b; b.u4 = woutlds[(v*8 + k)*64 + l];
        pacc = __builtin_amdgcn_mfma_f32_16x16x32_f16(Aho[k].v, b.v, pacc, 0, 0, 0);
      }
      #pragma unroll
      for (int k = 0; k < 4; ++k){          // peer-half K slots 4-7
        H8 b; b.u4 = woutlds[(v*8 + 4 + k)*64 + l];
        pacc = __builtin_amdgcn_mfma_f32_16x16x32_f16(Ahp[k].v, b.v, pacc, 0, 0, 0);
      }
      const int col = v*16 + c;
      #pragma unroll
      for (int r = 0; r < 4; ++r){
        const float pv = fsig(pacc[r] + bov);
        const int m = quad*4 + r;
        predlds[m][col] = (_Float16)pv;
        if (col < 88)
          __builtin_nontemporal_store(pv,
            dout + ((u64)(g*16 + m)*1024u + (u64)(t-1))*88u + col);
      }
    }
    __syncthreads();

    H8 Ap[3];
    if (t == 0){
      #pragma unroll
      for (int kt = 0; kt < 3; ++kt){ Ap[kt].q[0] = 0; Ap[kt].q[1] = 0; }
    } else {
      #pragma unroll
      for (int kt = 0; kt < 3; ++kt)
        Ap[kt].u4 = *(const v4u*)(&predlds[c][kt*32 + quad*8]);
    }

    v4f acc[4];
    #pragma unroll
    for (int nt = 0; nt < 4; ++nt) acc[nt] = (v4f){0.f,0.f,0.f,0.f};
    #pragma unroll
    for (int kt = 0; kt < 3; ++kt)
      #pragma unroll
      for (int nt = 0; nt < 4; ++nt)
        acc[nt] = __builtin_amdgcn_mfma_f32_16x16x32_f16(Ap[kt].v, Bw[nt][kt], acc[nt], 0, 0, 0);
    #pragma unroll
    for (int j = 0; j < 4; ++j)
      #pragma unroll
      for (int nt = 0; nt < 4; ++nt)
        acc[nt] = __builtin_amdgcn_mfma_f32_16x16x32_f16(Aho[j].v, Bw[nt][3 + j], acc[nt], 0, 0, 0);
    #pragma unroll
    for (int j = 0; j < 4; ++j)
      #pragma unroll
      for (int nt = 0; nt < 4; ++nt)
        acc[nt] = __builtin_amdgcn_mfma_f32_16x16x32_f16(Ahp[j].v, Bw[nt][7 + j], acc[nt], 0, 0, 0);

    u32* Lw = lbufp(wsu, g, p, t & 1);
    u32* Mw = mbufp(wsu, g, p, t & 1);
    const u32 wtg = TAG(1026 + t);
    #pragma unroll
    for (int r = 0; r < 4; ++r){
      const float gi = acc[0][r] + bd[0];
      const float gf = acc[1][r] + bd[1];
      const float gg = acc[2][r] + bd[2];
      const float go = acc[3][r] + bd[3];
      const float cn = fsig(gf)*cst[r] + fsig(gi)*ftanh(gg);
      cst[r] = cn;
      const float hn = fsig(go)*ftanh(cn);
      const int m = quad*4 + r;
      hlds[t & 1][m][lcol] = (_Float16)hn;
      const int off = m*128 + lcol;
      post(Lw + off, Mw + off, f2tag(hn, wtg));
    }
    __syncthreads();
  }

  // ---- tail: pred(1023) -> output row 1023 ----
  {
    H8 Aho[4], Ahp[4];
    const _Float16* hr = &hlds[1][c][0];
    #pragma unroll
    for (int j = 0; j < 4; ++j) Aho[j].u4 = *(const v4u*)(hr + 32*j + quad*8);
    read_peer(lbufp(wsu,g,1-p,1), mbufp(wsu,g,1-p,1), TAG(2049), c, quad, Ahp);
    if (v < 6){
      v4f pacc = (v4f){0.f,0.f,0.f,0.f};
      #pragma unroll
      for (int k = 0; k < 4; ++k){
        H8 b; b.u4 = woutlds[(v*8 + k)*64 + l];
        pacc = __builtin_amdgcn_mfma_f32_16x16x32_f16(Aho[k].v, b.v, pacc, 0, 0, 0);
      }
      #pragma unroll
      for (int k = 0; k < 4; ++k){
        H8 b; b.u4 = woutlds[(v*8 + 4 + k)*64 + l];
        pacc = __builtin_amdgcn_mfma_f32_16x16x32_f16(Ahp[k].v, b.v, pacc, 0, 0, 0);
      }
      const int col = v*16 + c;
      if (col < 88){
        #pragma unroll
        for (int r = 0; r < 4; ++r){
          const float pv = fsig(pacc[r] + bov);
          const int m = quad*4 + r;
          __builtin_nontemporal_store(pv,
            dout + ((u64)(g*16 + m)*1024u + 1023u)*88u + col);
        }
      }
    }
  }
}

extern "C" void kernel_launch(void* const* d_in, const int* in_sizes, int n_in,
                              void* d_out, int out_size, void* d_ws, size_t ws_size,
                              hipStream_t stream){
  (void)in_sizes; (void)n_in; (void)out_size; (void)ws_size;
  hipLaunchKernelGGL(lstm_ae, dim3(16), dim3(512), 0, stream,
    (const float*)d_in[0],  (const float*)d_in[1],  (const float*)d_in[2],
    (const float*)d_in[3],  (const float*)d_in[4],  (const float*)d_in[5],
    (const float*)d_in[6],  (const float*)d_in[7],  (const float*)d_in[8],
    (const float*)d_in[9],  (const float*)d_in[10], (const float*)d_in[11],
    (const float*)d_in[12], (const float*)d_in[13], (const float*)d_in[14],
    (float*)d_out, (char*)d_ws);
}

// Round 7
// 8763.069 us; speedup vs baseline: 3.0510x; 1.5288x over previous
//
#include <hip/hip_runtime.h>

// Persistent-kernel LSTM autoencoder for MI355X — round 7.
// Round-3 structure (8 groups x 16 WGs x 64 thr, 1 wave/WG, VGPR~244 no
// spill, tagged-word exchange, parity dbuf, no fences) + round-5/6's
// validated same-XCD exchange: block b -> group g = b&7, WG w = b>>3, so
// all 16 WGs of a group are ≡g (mod 8) => same XCD under round-robin
// dispatch (validated: FETCH collapsed 1.46GB -> 72MB in rounds 5/6).
// Producer dual-posts each tagged h word: sc0 (write-through to the local
// XCD L2) + sc0sc1 (MALL mirror). Consumer probes the local 16KB tile with
// 4 cached batched sc0 reads (shared-L2 hit), then falls back to the
// proven sc1 MALL poll. Correct on ANY XCD mapping via tags+parity.

typedef unsigned int u32;
typedef unsigned long long u64;
typedef unsigned short u16;

typedef _Float16 v8h __attribute__((ext_vector_type(8)));
typedef float    v4f __attribute__((ext_vector_type(4)));
typedef u32      v4u __attribute__((ext_vector_type(4)));

union H8 { v8h v; u64 q[2]; v4u u4; u32 d[4]; _Float16 h[8]; u16 s[8]; };

#define TAG(sid) (0x4000u + (u32)(sid))

// ws layout (u32 units):
//   Lbuf: [g][3 slots][16][256]  base 0      (group stride 12288)
//   Mbuf: same                   base 98304
//   zL:   [g][16][128]           base 196608 (group stride 2048)
//   zM:   same                   base 212992
#define LB(g,slot)  ((u64)(g)*12288u + (u64)(slot)*4096u)
#define MB(g,slot)  (98304u + (u64)(g)*12288u + (u64)(slot)*4096u)
#define ZL(g)       (196608u + (u64)(g)*2048u)
#define ZM(g)       (212992u + (u64)(g)*2048u)

static __device__ __forceinline__ float fsig(float x){
  return __builtin_amdgcn_rcpf(1.f + __builtin_amdgcn_exp2f(-1.4426950408889634f*x));
}
static __device__ __forceinline__ float ftanh(float x){
  return 1.f - 2.f*__builtin_amdgcn_rcpf(1.f + __builtin_amdgcn_exp2f(2.8853900817779268f*x));
}
static __device__ __forceinline__ u32 f2tag(float f, u32 tag){
  union{ _Float16 h; u16 b; } u; u.h = (_Float16)f;
  return (tag << 16) | (u32)u.b;
}

// Dual post: local-L2 copy (sc0 write-through) + MALL mirror (sc0 sc1).
static __device__ __forceinline__ void post(u32* lp, u32* mp, u32 v){
  asm volatile("global_store_dword %0, %2, off sc0\n\t"
               "global_store_dword %1, %2, off sc0 sc1"
               :: "v"(lp), "v"(mp), "v"(v) : "memory");
}

// Batched 16-KB tile read, L1-bypass, L2-CACHED (fast same-XCD path).
static __device__ __forceinline__ void ld16_fast(const u32* p, v4u q[16]){
  asm volatile(
    "global_load_dwordx4 %0, %16, off sc0\n\t"
    "global_load_dwordx4 %1, %16, off offset:16 sc0\n\t"
    "global_load_dwordx4 %2, %16, off offset:128 sc0\n\t"
    "global_load_dwordx4 %3, %16, off offset:144 sc0\n\t"
    "global_load_dwordx4 %4, %16, off offset:256 sc0\n\t"
    "global_load_dwordx4 %5, %16, off offset:272 sc0\n\t"
    "global_load_dwordx4 %6, %16, off offset:384 sc0\n\t"
    "global_load_dwordx4 %7, %16, off offset:400 sc0\n\t"
    "global_load_dwordx4 %8, %16, off offset:512 sc0\n\t"
    "global_load_dwordx4 %9, %16, off offset:528 sc0\n\t"
    "global_load_dwordx4 %10, %16, off offset:640 sc0\n\t"
    "global_load_dwordx4 %11, %16, off offset:656 sc0\n\t"
    "global_load_dwordx4 %12, %16, off offset:768 sc0\n\t"
    "global_load_dwordx4 %13, %16, off offset:784 sc0\n\t"
    "global_load_dwordx4 %14, %16, off offset:896 sc0\n\t"
    "global_load_dwordx4 %15, %16, off offset:912 sc0\n\t"
    "s_waitcnt vmcnt(0)"
    : "=v"(q[0]), "=v"(q[1]), "=v"(q[2]), "=v"(q[3]),
      "=v"(q[4]), "=v"(q[5]), "=v"(q[6]), "=v"(q[7]),
      "=v"(q[8]), "=v"(q[9]), "=v"(q[10]), "=v"(q[11]),
      "=v"(q[12]), "=v"(q[13]), "=v"(q[14]), "=v"(q[15])
    : "v"(p) : "memory");
}
// L2-bypass (MALL) variant — the proven round-3 fallback path.
static __device__ __forceinline__ void ld16_slow(const u32* p, v4u q[16]){
  asm volatile(
    "global_load_dwordx4 %0, %16, off sc0 sc1\n\t"
    "global_load_dwordx4 %1, %16, off offset:16 sc0 sc1\n\t"
    "global_load_dwordx4 %2, %16, off offset:128 sc0 sc1\n\t"
    "global_load_dwordx4 %3, %16, off offset:144 sc0 sc1\n\t"
    "global_load_dwordx4 %4, %16, off offset:256 sc0 sc1\n\t"
    "global_load_dwordx4 %5, %16, off offset:272 sc0 sc1\n\t"
    "global_load_dwordx4 %6, %16, off offset:384 sc0 sc1\n\t"
    "global_load_dwordx4 %7, %16, off offset:400 sc0 sc1\n\t"
    "global_load_dwordx4 %8, %16, off offset:512 sc0 sc1\n\t"
    "global_load_dwordx4 %9, %16, off offset:528 sc0 sc1\n\t"
    "global_load_dwordx4 %10, %16, off offset:640 sc0 sc1\n\t"
    "global_load_dwordx4 %11, %16, off offset:656 sc0 sc1\n\t"
    "global_load_dwordx4 %12, %16, off offset:768 sc0 sc1\n\t"
    "global_load_dwordx4 %13, %16, off offset:784 sc0 sc1\n\t"
    "global_load_dwordx4 %14, %16, off offset:896 sc0 sc1\n\t"
    "global_load_dwordx4 %15, %16, off offset:912 sc0 sc1\n\t"
    "s_waitcnt vmcnt(0)"
    : "=v"(q[0]), "=v"(q[1]), "=v"(q[2]), "=v"(q[3]),
      "=v"(q[4]), "=v"(q[5]), "=v"(q[6]), "=v"(q[7]),
      "=v"(q[8]), "=v"(q[9]), "=v"(q[10]), "=v"(q[11]),
      "=v"(q[12]), "=v"(q[13]), "=v"(q[14]), "=v"(q[15])
    : "v"(p) : "memory");
}
static __device__ __forceinline__ void ld8_fast(const u32* p, v4u q[8]){
  asm volatile(
    "global_load_dwordx4 %0, %8, off sc0\n\t"
    "global_load_dwordx4 %1, %8, off offset:16 sc0\n\t"
    "global_load_dwordx4 %2, %8, off offset:128 sc0\n\t"
    "global_load_dwordx4 %3, %8, off offset:144 sc0\n\t"
    "global_load_dwordx4 %4, %8, off offset:256 sc0\n\t"
    "global_load_dwordx4 %5, %8, off offset:272 sc0\n\t"
    "global_load_dwordx4 %6, %8, off offset:384 sc0\n\t"
    "global_load_dwordx4 %7, %8, off offset:400 sc0\n\t"
    "s_waitcnt vmcnt(0)"
    : "=v"(q[0]), "=v"(q[1]), "=v"(q[2]), "=v"(q[3]),
      "=v"(q[4]), "=v"(q[5]), "=v"(q[6]), "=v"(q[7])
    : "v"(p) : "memory");
}
static __device__ __forceinline__ void ld8_slow(const u32* p, v4u q[8]){
  asm volatile(
    "global_load_dwordx4 %0, %8, off sc0 sc1\n\t"
    "global_load_dwordx4 %1, %8, off offset:16 sc0 sc1\n\t"
    "global_load_dwordx4 %2, %8, off offset:128 sc0 sc1\n\t"
    "global_load_dwordx4 %3, %8, off offset:144 sc0 sc1\n\t"
    "global_load_dwordx4 %4, %8, off offset:256 sc0 sc1\n\t"
    "global_load_dwordx4 %5, %8, off offset:272 sc0 sc1\n\t"
    "global_load_dwordx4 %6, %8, off offset:384 sc0 sc1\n\t"
    "global_load_dwordx4 %7, %8, off offset:400 sc0 sc1\n\t"
    "s_waitcnt vmcnt(0)"
    : "=v"(q[0]), "=v"(q[1]), "=v"(q[2]), "=v"(q[3]),
      "=v"(q[4]), "=v"(q[5]), "=v"(q[6]), "=v"(q[7])
    : "v"(p) : "memory");
}

static __device__ __forceinline__ bool tags_ok16(const v4u q[16], u32 tm){
  u32 bad = 0;
  #pragma unroll
  for (int i = 0; i < 16; ++i)
    #pragma unroll
    for (int j = 0; j < 4; ++j) bad |= (q[i][j] ^ tm);
  return __all((bad & 0xFFFF0000u) == 0);
}
static __device__ __forceinline__ void pack16(const v4u q[16], H8 A[8]){
  #pragma unroll
  for (int k = 0; k < 8; ++k){
    const v4u a = q[2*k], b = q[2*k+1];
    A[k].d[0] = (a[0] & 0xFFFFu) | (a[1] << 16);
    A[k].d[1] = (a[2] & 0xFFFFu) | (a[3] << 16);
    A[k].d[2] = (b[0] & 0xFFFFu) | (b[1] << 16);
    A[k].d[3] = (b[2] & 0xFFFFu) | (b[3] << 16);
  }
}
static __device__ __forceinline__ bool tags_ok8(const v4u q[8], u32 tm){
  u32 bad = 0;
  #pragma unroll
  for (int i = 0; i < 8; ++i)
    #pragma unroll
    for (int j = 0; j < 4; ++j) bad |= (q[i][j] ^ tm);
  return __all((bad & 0xFFFF0000u) == 0);
}
static __device__ __forceinline__ void pack8(const v4u q[8], H8 A[4]){
  #pragma unroll
  for (int k = 0; k < 4; ++k){
    const v4u a = q[2*k], b = q[2*k+1];
    A[k].d[0] = (a[0] & 0xFFFFu) | (a[1] << 16);
    A[k].d[1] = (a[2] & 0xFFFFu) | (a[3] << 16);
    A[k].d[2] = (b[0] & 0xFFFFu) | (b[1] << 16);
    A[k].d[3] = (b[2] & 0xFFFFu) | (b[3] << 16);
  }
}

// Poll one tagged 16x256 tile: 4 local-L2 probes, then MALL-mirror loop.
static __device__ __forceinline__ void read_tile256(const u32* lb, const u32* mb,
                                                    u32 tag, int c, int quad, H8 Ah[8]){
  const int off = c*256 + quad*8;
  const u32 tm = tag << 16;
  v4u q[16];
  #pragma unroll 1
  for (int a = 0; a < 4; ++a){
    ld16_fast(lb + off, q);
    if (tags_ok16(q, tm)){ pack16(q, Ah); return; }
  }
  #pragma unroll 1
  for(;;){
    ld16_slow(mb + off, q);
    if (tags_ok16(q, tm)){ pack16(q, Ah); return; }
    __builtin_amdgcn_s_sleep(1);
  }
}

static __device__ __forceinline__ void read_tile128(const u32* lb, const u32* mb,
                                                    u32 tag, int c, int quad, H8 Az[4]){
  const int off = c*128 + quad*8;
  const u32 tm = tag << 16;
  v4u q[8];
  #pragma unroll 1
  for (int a = 0; a < 4; ++a){
    ld8_fast(lb + off, q);
    if (tags_ok8(q, tm)){ pack8(q, Az); return; }
  }
  #pragma unroll 1
  for(;;){
    ld8_slow(mb + off, q);
    if (tags_ok8(q, tm)){ pack8(q, Az); return; }
    __builtin_amdgcn_s_sleep(1);
  }
}

// 4x11 B-fragments (N=[i16|f16|g16|o16], K=[inp 0..95 pad | h 96..351]).
static __device__ __forceinline__ void build_Bw(v8h Bw[4][11], const float* Wih,
                                                const float* Whh, int wcol, int quad){
  #pragma unroll
  for (int nt = 0; nt < 4; ++nt){
    const int n = nt*256 + wcol;
    #pragma unroll
    for (int kt = 0; kt < 11; ++kt){
      const int k0 = kt*32 + quad*8;
      H8 a;
      #pragma unroll
      for (int j = 0; j < 8; ++j){
        const int k = k0 + j;
        float v;
        if (kt < 3) v = (k < 88) ? Wih[n*88 + k] : 0.f;
        else        v = Whh[n*256 + (k - 96)];
        a.h[j] = (_Float16)v;
      }
      Bw[nt][kt] = a.v;
    }
  }
}

__global__ __launch_bounds__(64, 1) void lstm_ae(
    const float* __restrict__ x,
    const float* __restrict__ Wih_e, const float* __restrict__ Whh_e,
    const float* __restrict__ bih_e, const float* __restrict__ bhh_e,
    const float* __restrict__ Wih_d, const float* __restrict__ Whh_d,
    const float* __restrict__ bih_d, const float* __restrict__ bhh_d,
    const float* __restrict__ W_lat, const float* __restrict__ b_lat,
    const float* __restrict__ W_decinit, const float* __restrict__ b_decinit,
    const float* __restrict__ W_out, const float* __restrict__ b_out,
    float* __restrict__ dout, char* __restrict__ ws)
{
  const int l = (int)threadIdx.x;
  const int c = l & 15, quad = l >> 4;
  const int bid = (int)blockIdx.x;
  const int g = bid & 7, w = bid >> 3;   // all WGs of group g on XCD g (heuristic)
  const int wcol = w*16 + c;

  u32* wsu = (u32*)ws;

  __shared__ v4u      woutlds[3072];    // 48 KB: W_out fp16 B-frags
  __shared__ _Float16 predlds[16*104];

  // ---- prologue: W_out -> LDS fragments ----
  #pragma unroll 4
  for (int fid = 0; fid < 48; ++fid){
    const int nt = fid >> 3, kt = fid & 7;
    const int n = nt*16 + c, k0 = kt*32 + quad*8;
    H8 a;
    #pragma unroll
    for (int j = 0; j < 8; ++j){
      float v = (n < 88) ? W_out[n*256 + k0 + j] : 0.f;
      a.h[j] = (_Float16)v;
    }
    woutlds[fid*64 + l] = a.u4;
  }
  __syncthreads();

  v8h Bw[4][11];
  build_Bw(Bw, Wih_e, Whh_e, wcol, quad);
  float be[4];
  #pragma unroll
  for (int nt = 0; nt < 4; ++nt){ const int n = nt*256 + wcol; be[nt] = bih_e[n] + bhh_e[n]; }

  float cst[4] = {0.f, 0.f, 0.f, 0.f};

  // ================= encoder =================
  #pragma unroll 1
  for (int t = 0; t < 1024; ++t){
    H8 Ax[3];
    {
      const float* xb = x + ((u64)(g*16 + c)*1024u + (u64)t)*88u;
      #pragma unroll
      for (int kt = 0; kt < 3; ++kt){
        const int k0 = kt*32 + quad*8;
        if (kt == 2 && quad == 3){ Ax[kt].q[0] = 0; Ax[kt].q[1] = 0; }
        else {
          v4f f0 = *(const v4f*)(xb + k0);
          v4f f1 = *(const v4f*)(xb + k0 + 4);
          #pragma unroll
          for (int j = 0; j < 4; ++j){ Ax[kt].h[j] = (_Float16)f0[j]; Ax[kt].h[j+4] = (_Float16)f1[j]; }
        }
      }
    }

    H8 Ah[8];
    if (t > 0)
      read_tile256(wsu + LB(g,(t-1)&1), wsu + MB(g,(t-1)&1), TAG(t-1), c, quad, Ah);

    v4f acc[4];
    #pragma unroll
    for (int nt = 0; nt < 4; ++nt) acc[nt] = (v4f){0.f,0.f,0.f,0.f};

    #pragma unroll
    for (int kt = 0; kt < 3; ++kt)
      #pragma unroll
      for (int nt = 0; nt < 4; ++nt)
        acc[nt] = __builtin_amdgcn_mfma_f32_16x16x32_f16(Ax[kt].v, Bw[nt][kt], acc[nt], 0, 0, 0);

    if (t > 0){
      #pragma unroll
      for (int kt = 0; kt < 8; ++kt)
        #pragma unroll
        for (int nt = 0; nt < 4; ++nt)
          acc[nt] = __builtin_amdgcn_mfma_f32_16x16x32_f16(Ah[kt].v, Bw[nt][kt+3], acc[nt], 0, 0, 0);
    }

    u32* Lw = wsu + LB(g, t&1);
    u32* Mw = wsu + MB(g, t&1);
    const u32 tg = TAG(t);
    #pragma unroll
    for (int r = 0; r < 4; ++r){
      const float gi = acc[0][r] + be[0];
      const float gf = acc[1][r] + be[1];
      const float gg = acc[2][r] + be[2];
      const float go = acc[3][r] + be[3];
      const float cn = fsig(gf)*cst[r] + fsig(gi)*ftanh(gg);
      cst[r] = cn;
      const float hn = fsig(go)*ftanh(cn);
      const int off = (quad*4+r)*256 + wcol;
      post(Lw + off, Mw + off, f2tag(hn, tg));
    }
  }

  // ---- switch weights to decoder ----
  build_Bw(Bw, Wih_d, Whh_d, wcol, quad);
  float bd[4];
  #pragma unroll
  for (int nt = 0; nt < 4; ++nt){ const int n = nt*256 + wcol; bd[nt] = bih_d[n] + bhh_d[n]; }
  float bo[6];
  #pragma unroll
  for (int nt = 0; nt < 6; ++nt){ const int n = nt*16 + c; bo[nt] = (n < 88) ? b_out[n] : 0.f; }

  // ---- latent: z = h_n @ W_lat.T + b_lat (WGs 0..7) ----
  if (w < 8){
    H8 Ah[8];
    read_tile256(wsu + LB(g,1), wsu + MB(g,1), TAG(1023), c, quad, Ah);
    v4f zacc = (v4f){0.f,0.f,0.f,0.f};
    const int n = wcol;  // < 128
    #pragma unroll
    for (int kt = 0; kt < 8; ++kt){
      H8 b;
      const int k0 = kt*32 + quad*8;
      v4f f0 = *(const v4f*)(W_lat + n*256 + k0);
      v4f f1 = *(const v4f*)(W_lat + n*256 + k0 + 4);
      #pragma unroll
      for (int j = 0; j < 4; ++j){ b.h[j] = (_Float16)f0[j]; b.h[j+4] = (_Float16)f1[j]; }
      zacc = __builtin_amdgcn_mfma_f32_16x16x32_f16(Ah[kt].v, b.v, zacc, 0, 0, 0);
    }
    const float bl = b_lat[n];
    u32* zLw = wsu + ZL(g);
    u32* zMw = wsu + ZM(g);
    #pragma unroll
    for (int r = 0; r < 4; ++r){
      const int m = quad*4 + r;
      const float zv = zacc[r] + bl;
      __builtin_nontemporal_store(zv, dout + 11534336u + (u64)(g*16 + m)*128u + n);
      const int off = m*128 + n;
      post(zLw + off, zMw + off, f2tag(zv, TAG(1024)));
    }
  }

  // ---- decoder init: h0 = z @ W_decinit.T + b_decinit (all 16 WGs) ----
  {
    H8 Az[4];
    read_tile128(wsu + ZL(g), wsu + ZM(g), TAG(1024), c, quad, Az);
    const int n = wcol;
    v4f da = (v4f){0.f,0.f,0.f,0.f};
    #pragma unroll
    for (int kt = 0; kt < 4; ++kt){
      H8 b;
      const int k0 = kt*32 + quad*8;
      v4f f0 = *(const v4f*)(W_decinit + n*128 + k0);
      v4f f1 = *(const v4f*)(W_decinit + n*128 + k0 + 4);
      #pragma unroll
      for (int j = 0; j < 4; ++j){ b.h[j] = (_Float16)f0[j]; b.h[j+4] = (_Float16)f1[j]; }
      da = __builtin_amdgcn_mfma_f32_16x16x32_f16(Az[kt].v, b.v, da, 0, 0, 0);
    }
    const float bdi = b_decinit[n];
    u32* Lw = wsu + LB(g,2);
    u32* Mw = wsu + MB(g,2);
    #pragma unroll
    for (int r = 0; r < 4; ++r){
      const float hv = da[r] + bdi;
      const int off = (quad*4+r)*256 + wcol;
      post(Lw + off, Mw + off, f2tag(hv, TAG(1025)));
    }
  }

  #pragma unroll
  for (int r = 0; r < 4; ++r) cst[r] = 0.f;

  // ================= decoder =================
  #pragma unroll 1
  for (int t = 0; t < 1024; ++t){
    const u32 tg = TAG(1025 + t);
    const int gsl = (t == 0) ? 2 : ((t-1)&1);
    H8 Ah[8];
    read_tile256(wsu + LB(g,gsl), wsu + MB(g,gsl), tg, c, quad, Ah);

    if (t > 0){
      // pred(t-1) = sigmoid(W_out @ h(t-1) + b_out), redundant per WG
      v4f pacc[6];
      #pragma unroll
      for (int nt = 0; nt < 6; ++nt) pacc[nt] = (v4f){0.f,0.f,0.f,0.f};
      #pragma unroll
      for (int nt = 0; nt < 6; ++nt)
        #pragma unroll
        for (int kt = 0; kt < 8; ++kt){
          H8 b; b.u4 = woutlds[(nt*8 + kt)*64 + l];
          pacc[nt] = __builtin_amdgcn_mfma_f32_16x16x32_f16(Ah[kt].v, b.v, pacc[nt], 0, 0, 0);
        }
      const bool wr = (w < 11) && ((c >> 3) == (w & 1));
      #pragma unroll
      for (int nt = 0; nt < 6; ++nt)
        #pragma unroll
        for (int r = 0; r < 4; ++r){
          const float pv = fsig(pacc[nt][r] + bo[nt]);
          const int m = quad*4 + r;
          predlds[m*104 + nt*16 + c] = (_Float16)pv;
          if (wr && nt == (w >> 1))
            __builtin_nontemporal_store(pv,
              dout + ((u64)(g*16 + m)*1024u + (u64)(t-1))*88u + 8*w + (c & 7));
        }
    }
    __syncthreads();

    H8 Ap[3];
    if (t == 0){
      #pragma unroll
      for (int kt = 0; kt < 3; ++kt){ Ap[kt].q[0] = 0; Ap[kt].q[1] = 0; }
    } else {
      #pragma unroll
      for (int kt = 0; kt < 3; ++kt)
        Ap[kt].u4 = *(const v4u*)(&predlds[c*104 + kt*32 + quad*8]);
    }

    v4f acc[4];
    #pragma unroll
    for (int nt = 0; nt < 4; ++nt) acc[nt] = (v4f){0.f,0.f,0.f,0.f};
    #pragma unroll
    for (int kt = 0; kt < 3; ++kt)
      #pragma unroll
      for (int nt = 0; nt < 4; ++nt)
        acc[nt] = __builtin_amdgcn_mfma_f32_16x16x32_f16(Ap[kt].v, Bw[nt][kt], acc[nt], 0, 0, 0);
    #pragma unroll
    for (int kt = 0; kt < 8; ++kt)
      #pragma unroll
      for (int nt = 0; nt < 4; ++nt)
        acc[nt] = __builtin_amdgcn_mfma_f32_16x16x32_f16(Ah[kt].v, Bw[nt][kt+3], acc[nt], 0, 0, 0);

    u32* Lw = wsu + LB(g, t&1);
    u32* Mw = wsu + MB(g, t&1);
    const u32 wtg = TAG(1026 + t);
    #pragma unroll
    for (int r = 0; r < 4; ++r){
      const float gi = acc[0][r] + bd[0];
      const float gf = acc[1][r] + bd[1];
      const float gg = acc[2][r] + bd[2];
      const float go = acc[3][r] + bd[3];
      const float cn = fsig(gf)*cst[r] + fsig(gi)*ftanh(gg);
      cst[r] = cn;
      const float hn = fsig(go)*ftanh(cn);
      const int off = (quad*4+r)*256 + wcol;
      post(Lw + off, Mw + off, f2tag(hn, wtg));
    }
  }

  // ---- tail: pred(1023) -> output row 1023 ----
  {
    H8 Ah[8];
    read_tile256(wsu + LB(g,1), wsu + MB(g,1), TAG(2049), c, quad, Ah);
    v4f pacc[6];
    #pragma unroll
    for (int nt = 0; nt < 6; ++nt) pacc[nt] = (v4f){0.f,0.f,0.f,0.f};
    #pragma unroll
    for (int nt = 0; nt < 6; ++nt)
      #pragma unroll
      for (int kt = 0; kt < 8; ++kt){
        H8 b; b.u4 = woutlds[(nt*8 + kt)*64 + l];
        pacc[nt] = __builtin_amdgcn_mfma_f32_16x16x32_f16(Ah[kt].v, b.v, pacc[nt], 0, 0, 0);
      }
    const bool wr = (w < 11) && ((c >> 3) == (w & 1));
    if (wr){
      const int nt = w >> 1;
      #pragma unroll
      for (int r = 0; r < 4; ++r){
        const float pv = fsig(pacc[nt][r] + bo[nt]);
        const int m = quad*4 + r;
        __builtin_nontemporal_store(pv,
          dout + ((u64)(g*16 + m)*1024u + 1023u)*88u + 8*w + (c & 7));
      }
    }
  }
}

extern "C" void kernel_launch(void* const* d_in, const int* in_sizes, int n_in,
                              void* d_out, int out_size, void* d_ws, size_t ws_size,
                              hipStream_t stream){
  (void)in_sizes; (void)n_in; (void)out_size; (void)ws_size;
  hipLaunchKernelGGL(lstm_ae, dim3(128), dim3(64), 0, stream,
    (const float*)d_in[0],  (const float*)d_in[1],  (const float*)d_in[2],
    (const float*)d_in[3],  (const float*)d_in[4],  (const float*)d_in[5],
    (const float*)d_in[6],  (const float*)d_in[7],  (const float*)d_in[8],
    (const float*)d_in[9],  (const float*)d_in[10], (const float*)d_in[11],
    (const float*)d_in[12], (const float*)d_in[13], (const float*)d_in[14],
    (float*)d_out, (char*)d_ws);
}